// Round 12
// baseline (113.875 us; speedup 1.0000x reference)
//
#include <hip/hip_runtime.h>
#include <math.h>

#define BB 16

typedef __attribute__((ext_vector_type(8))) unsigned short ushort8;
typedef __attribute__((ext_vector_type(8))) short short8v;
typedef __attribute__((ext_vector_type(4))) float f32x4;

__device__ __forceinline__ float sigf(float x) { return 1.0f / (1.0f + __expf(-x)); }

__device__ __forceinline__ float bf2f(unsigned short s) {
    return __uint_as_float(((unsigned int)s) << 16);
}
__device__ __forceinline__ unsigned short f2bf(float f) {
    return (unsigned short)((__float_as_uint(f) + 0x8000u) >> 16);
}

#define WAVE_WAIT() asm volatile("s_waitcnt lgkmcnt(0)" ::: "memory")

// ================= Kernel A v5 (unchanged): one WAVE per row =================
__global__ __launch_bounds__(256) void ka_attention_v5(
    const float* __restrict__ self_feat,
    const float* __restrict__ entities,
    const void*  __restrict__ mask_raw,
    const float* __restrict__ W_se, const float* __restrict__ b_se,
    const float* __restrict__ W_ee, const float* __restrict__ b_ee,
    const float* __restrict__ W_q,  const float* __restrict__ b_q,
    const float* __restrict__ W_k,  const float* __restrict__ b_k,
    const float* __restrict__ W_v,  const float* __restrict__ b_v,
    float* out)
{
    const int t = threadIdx.x;
    const int l = t & 63;
    const int w = __builtin_amdgcn_readfirstlane(t >> 6);
    const int b = blockIdx.x * 4 + w;

    __shared__ float s_wee[768];
    __shared__ __align__(16) unsigned short s_tile[4][64][64];
    __shared__ __align__(16) float s_qk[4][64][4];
    __shared__ __align__(16) float s_p[4][64][4];
    __shared__ __align__(16) float s_ctx[4][64][4];
    __shared__ float s_emb[4][64];
    __shared__ float s_q[4][64];

    s_wee[t]       = W_ee[t];
    s_wee[t + 256] = W_ee[t + 256];
    s_wee[t + 512] = W_ee[t + 512];

    bool mask_is_int = true;
    {
        const unsigned int* mw = (const unsigned int*)mask_raw;
        #pragma unroll
        for (int w0 = 0; w0 < 64; ++w0) mask_is_int = mask_is_int && (mw[w0] <= 1u);
    }

    __syncthreads();

    float emb = b_se[l];
    {
        const float* sfp = self_feat + (size_t)b * 24;
        #pragma unroll
        for (int i = 0; i < 24; ++i) emb = fmaf(sfp[i], W_se[i * 64 + l], emb);
        emb = fmaxf(emb, 0.0f);
    }
    s_emb[w][l] = emb;
    WAVE_WAIT();

    float qv = b_q[l];
    #pragma unroll
    for (int i4 = 0; i4 < 16; ++i4) {
        const float4 ev = *(const float4*)&s_emb[w][i4 * 4];
        qv = fmaf(ev.x, W_q[(i4 * 4 + 0) * 64 + l], qv);
        qv = fmaf(ev.y, W_q[(i4 * 4 + 1) * 64 + l], qv);
        qv = fmaf(ev.z, W_q[(i4 * 4 + 2) * 64 + l], qv);
        qv = fmaf(ev.w, W_q[(i4 * 4 + 3) * 64 + l], qv);
    }
    s_q[w][l] = qv;

    float vb = qv * b_k[l];
    vb += __shfl_xor(vb, 1); vb += __shfl_xor(vb, 2);
    vb += __shfl_xor(vb, 4); vb += __shfl_xor(vb, 8);
    const float qb0 = __shfl(vb, 0),  qb1 = __shfl(vb, 16);
    const float qb2 = __shfl(vb, 32), qb3 = __shfl(vb, 48);
    WAVE_WAIT();

    {
        const int hh = l & 3;
        #pragma unroll
        for (int g = 0; g < 4; ++g) {
            const int i = g * 16 + (l >> 2);
            const float* wk = W_k + i * 64 + hh * 16;
            float acc = 0.0f;
            #pragma unroll
            for (int j4 = 0; j4 < 4; ++j4) {
                const float4 kv = *(const float4*)(wk + j4 * 4);
                const float4 qq = *(const float4*)&s_q[w][hh * 16 + j4 * 4];
                acc = fmaf(kv.x, qq.x, acc); acc = fmaf(kv.y, qq.y, acc);
                acc = fmaf(kv.z, qq.z, acc); acc = fmaf(kv.w, qq.w, acc);
            }
            s_qk[w][i][hh] = acc;
        }
    }

    float m0 = -1e30f, m1 = -1e30f, m2 = -1e30f, m3 = -1e30f;
    float ll0 = 0.f, ll1 = 0.f, ll2 = 0.f, ll3 = 0.f;
    float ctx0 = 0.f, ctx1 = 0.f, ctx2 = 0.f, ctx3 = 0.f;

    const float4* beev = (const float4*)b_ee;

    #pragma unroll 1
    for (int pass = 0; pass < 2; ++pass) {
        const int n = pass * 64 + l;

        bool msk;
        if (mask_is_int) msk = ((const int*)mask_raw)[(size_t)b * 128 + n] != 0;
        else             msk = ((const unsigned char*)mask_raw)[(size_t)b * 128 + n] != 0;

        const float* ep = entities + (size_t)b * 1536 + n * 12;
        const float4 e0 = *(const float4*)ep;
        const float4 e1 = *(const float4*)(ep + 4);
        const float4 e2 = *(const float4*)(ep + 8);

        float4 ee4[16];
        #pragma unroll
        for (int d4 = 0; d4 < 16; ++d4) ee4[d4] = beev[d4];
        #define ENC(EIV, ROW)                                                  \
            { const float eiv_ = (EIV);                                        \
              _Pragma("unroll")                                                \
              for (int d4 = 0; d4 < 16; ++d4) {                                \
                  const float4 wv = *(const float4*)&s_wee[(ROW) * 64 + d4*4]; \
                  ee4[d4].x = fmaf(eiv_, wv.x, ee4[d4].x);                     \
                  ee4[d4].y = fmaf(eiv_, wv.y, ee4[d4].y);                     \
                  ee4[d4].z = fmaf(eiv_, wv.z, ee4[d4].z);                     \
                  ee4[d4].w = fmaf(eiv_, wv.w, ee4[d4].w); } }
        ENC(e0.x, 0)  ENC(e0.y, 1)  ENC(e0.z, 2)  ENC(e0.w, 3)
        ENC(e1.x, 4)  ENC(e1.y, 5)  ENC(e1.z, 6)  ENC(e1.w, 7)
        ENC(e2.x, 8)  ENC(e2.y, 9)  ENC(e2.z, 10) ENC(e2.w, 11)
        #undef ENC

        #pragma unroll
        for (int c8 = 0; c8 < 8; ++c8) {
            const float4 a = ee4[c8 * 2], c = ee4[c8 * 2 + 1];
            ushort8 sv;
            sv[0] = f2bf(fmaxf(a.x, 0.f)); sv[1] = f2bf(fmaxf(a.y, 0.f));
            sv[2] = f2bf(fmaxf(a.z, 0.f)); sv[3] = f2bf(fmaxf(a.w, 0.f));
            sv[4] = f2bf(fmaxf(c.x, 0.f)); sv[5] = f2bf(fmaxf(c.y, 0.f));
            sv[6] = f2bf(fmaxf(c.z, 0.f)); sv[7] = f2bf(fmaxf(c.w, 0.f));
            *(ushort8*)&s_tile[w][l][(c8 ^ (l & 7)) << 3] = sv;
        }
        WAVE_WAIT();

        float sc0 = 0.f, sc1 = 0.f, sc2 = 0.f, sc3 = 0.f;
        #pragma unroll
        for (int c8 = 0; c8 < 8; ++c8) {
            const ushort8 evv = *(const ushort8*)&s_tile[w][l][(c8 ^ (l & 7)) << 3];
            #pragma unroll
            for (int k = 0; k < 8; ++k) {
                const float e = bf2f(evv[k]);
                const float4 qk = *(const float4*)&s_qk[w][c8 * 8 + k][0];
                sc0 = fmaf(e, qk.x, sc0); sc1 = fmaf(e, qk.y, sc1);
                sc2 = fmaf(e, qk.z, sc2); sc3 = fmaf(e, qk.w, sc3);
            }
        }
        sc0 = msk ? (sc0 + qb0) * 0.25f : -1e30f;
        sc1 = msk ? (sc1 + qb1) * 0.25f : -1e30f;
        sc2 = msk ? (sc2 + qb2) * 0.25f : -1e30f;
        sc3 = msk ? (sc3 + qb3) * 0.25f : -1e30f;

        float t0 = sc0, t1 = sc1, t2 = sc2, t3 = sc3;
        #pragma unroll
        for (int d = 1; d < 64; d <<= 1) {
            t0 = fmaxf(t0, __shfl_xor(t0, d)); t1 = fmaxf(t1, __shfl_xor(t1, d));
            t2 = fmaxf(t2, __shfl_xor(t2, d)); t3 = fmaxf(t3, __shfl_xor(t3, d));
        }
        const float mn0 = fmaxf(m0, t0), mn1 = fmaxf(m1, t1);
        const float mn2 = fmaxf(m2, t2), mn3 = fmaxf(m3, t3);
        const float sl0 = __expf(m0 - mn0), sl1 = __expf(m1 - mn1);
        const float sl2 = __expf(m2 - mn2), sl3 = __expf(m3 - mn3);
        const float p0 = msk ? __expf(sc0 - mn0) : 0.0f;
        const float p1 = msk ? __expf(sc1 - mn1) : 0.0f;
        const float p2 = msk ? __expf(sc2 - mn2) : 0.0f;
        const float p3 = msk ? __expf(sc3 - mn3) : 0.0f;
        float ps0 = p0, ps1 = p1, ps2 = p2, ps3 = p3;
        #pragma unroll
        for (int d = 1; d < 64; d <<= 1) {
            ps0 += __shfl_xor(ps0, d); ps1 += __shfl_xor(ps1, d);
            ps2 += __shfl_xor(ps2, d); ps3 += __shfl_xor(ps3, d);
        }
        ll0 = ll0 * sl0 + ps0; ll1 = ll1 * sl1 + ps1;
        ll2 = ll2 * sl2 + ps2; ll3 = ll3 * sl3 + ps3;
        m0 = mn0; m1 = mn1; m2 = mn2; m3 = mn3;

        { float4 pv; pv.x = p0; pv.y = p1; pv.z = p2; pv.w = p3;
          *(float4*)&s_p[w][l][0] = pv; }
        WAVE_WAIT();

        ctx0 *= sl0; ctx1 *= sl1; ctx2 *= sl2; ctx3 *= sl3;
        const int cb = (l >> 3) << 3, lo = l & 7;
        #pragma unroll 8
        for (int j = 0; j < 64; ++j) {
            const float4 pj = *(const float4*)&s_p[w][j][0];
            const float e = bf2f(s_tile[w][j][(cb ^ ((j & 7) << 3)) + lo]);
            ctx0 = fmaf(pj.x, e, ctx0); ctx1 = fmaf(pj.y, e, ctx1);
            ctx2 = fmaf(pj.z, e, ctx2); ctx3 = fmaf(pj.w, e, ctx3);
        }
        WAVE_WAIT();
    }

    {
        const float i0 = ll0 > 0.f ? 1.f / ll0 : 0.f;
        const float i1 = ll1 > 0.f ? 1.f / ll1 : 0.f;
        const float i2 = ll2 > 0.f ? 1.f / ll2 : 0.f;
        const float i3 = ll3 > 0.f ? 1.f / ll3 : 0.f;
        float4 cv; cv.x = ctx0 * i0; cv.y = ctx1 * i1; cv.z = ctx2 * i2; cv.w = ctx3 * i3;
        *(float4*)&s_ctx[w][l][0] = cv;
    }
    WAVE_WAIT();
    {
        const int h = l >> 4;
        float ao = b_v[l];
        #pragma unroll 8
        for (int i = 0; i < 64; ++i) ao = fmaf(s_ctx[w][i][h], W_v[i * 64 + l], ao);
        out[(size_t)b * 268 + 12 + l] = emb;
        out[(size_t)b * 268 + 76 + l] = ao;
    }
}

// ================= weight pack: fp32 -> bf16 in MFMA B-fragment order =======
// B-frag for mfma_f32_16x16x32_bf16: lane = (kgrp<<4)|n_l holds B[k][n] for
// n = ntile*16 + n_l, k = ktile*32 + kgrp*8 + j (j=0..7, one b128 per lane).
// Packed elem index: ((ntile*KT + ktile)*64 + lane)*8 + j.
#define PK_GATES 0          /* [W_ih;W_hh] as 256x512, KT=8  -> 131072 elems */
#define PK_P1    131072     /* 128x128, KT=4 -> 16384 */
#define PK_P2    147456
#define PK_WA    163840
#define PK_TOTAL 180224     /* ushorts; 360448 bytes */

__global__ __launch_bounds__(256) void pack_weights(
    const float* __restrict__ W_ih, const float* __restrict__ W_hh,
    const float* __restrict__ W_p1, const float* __restrict__ W_p2,
    const float* __restrict__ W_a,  unsigned short* __restrict__ dst)
{
    const int tid = blockIdx.x * 256 + threadIdx.x;
    const float* W; int N, KT, base, k_off, idx;
    if (tid < 65536)       { W = W_ih; N = 512; KT = 8; base = PK_GATES; k_off = 0;   idx = tid; }
    else if (tid < 131072) { W = W_hh; N = 512; KT = 8; base = PK_GATES; k_off = 128; idx = tid - 65536; }
    else if (tid < 147456) { W = W_p1; N = 128; KT = 4; base = PK_P1;    k_off = 0;   idx = tid - 131072; }
    else if (tid < 163840) { W = W_p2; N = 128; KT = 4; base = PK_P2;    k_off = 0;   idx = tid - 147456; }
    else                   { W = W_a;  N = 128; KT = 4; base = PK_WA;    k_off = 0;   idx = tid - 163840; }
    const int k0 = idx / N, n = idx - k0 * N;
    const int k = k0 + k_off;
    const int ntile = n >> 4, nl = n & 15;
    const int ktile = k >> 5, kg = (k >> 3) & 3, j = k & 7;
    const int lane = (kg << 4) | nl;
    dst[base + (((ntile * KT + ktile) * 64 + lane) << 3) + j] = f2bf(W[idx]);
}

// ================= MFMA GEMM helper: 16 rows x (NTW*16) cols, K = KT*32 =====
template<int KT, int NTW>
__device__ __forceinline__ void mfma_gemm(const unsigned short* sA, int lda,
                                          const unsigned short* __restrict__ wpk,
                                          int w, int l, f32x4* acc)
{
    const int mrow = l & 15, kg = l >> 4;
    #pragma unroll
    for (int nt = 0; nt < NTW; ++nt) {
        f32x4 a; a[0] = 0.f; a[1] = 0.f; a[2] = 0.f; a[3] = 0.f;
        const int ntile = w * NTW + nt;
        #pragma unroll
        for (int kt = 0; kt < KT; ++kt) {
            const short8v av = *(const short8v*)(sA + mrow * lda + kt * 32 + kg * 8);
            const short8v bv = *(const short8v*)(wpk + ((size_t)((ntile * KT + kt) * 64 + l) << 3));
            a = __builtin_amdgcn_mfma_f32_16x16x32_bf16(av, bv, a, 0, 0, 0);
        }
        acc[nt] = a;
    }
}

// ================= Kernel B v3: MFMA MLP + LSTM + heads (16 rows/block) =====
__global__ __launch_bounds__(256) void kb_lstm_mfma(
    const float* __restrict__ hx, const float* __restrict__ cx,
    const unsigned short* __restrict__ wpk,
    const float* __restrict__ b_p1, const float* __restrict__ b_p2,
    const float* __restrict__ b_ih, const float* __restrict__ b_hh,
    const float* __restrict__ b_a,
    const float* __restrict__ W_mx, const float* __restrict__ b_mx,
    const float* __restrict__ W_my, const float* __restrict__ b_my,
    const float* __restrict__ W_fi, const float* __restrict__ b_fi,
    const float* __restrict__ W_he, const float* __restrict__ b_he,
    const float* __restrict__ W_ra, const float* __restrict__ b_ra,
    const float* __restrict__ W_rb, const float* __restrict__ b_rb,
    float* out)
{
    const int t = threadIdx.x;
    const int l = t & 63;
    const int w = __builtin_amdgcn_readfirstlane(t >> 6);   // wave 0..3
    const int r0 = blockIdx.x * BB;
    const int mrow = l & 15, kg = l >> 4;

    __shared__ __align__(16) unsigned short s_a[BB][264];  // bf16 A: X|hx -> Y -> R|hx -> F
    __shared__ float s_r[BB][132];                          // reactive fp32
    __shared__ float s_g[BB][516];                          // gates fp32
    __shared__ float s_h[BB][132];                          // h fp32

    // ---- stage combined (bf16) + hx (bf16)
    for (int idx = t; idx < BB * 128; idx += 256) {
        const int r = idx >> 7, j = idx & 127;
        s_a[r][j]       = f2bf(out[(size_t)(r0 + r) * 268 + 12 + j]);
        s_a[r][128 + j] = f2bf(hx[(size_t)(r0 + r) * 128 + j]);
    }
    __syncthreads();

    f32x4 acc2[2];

    // ---- p1: Y = relu(X @ W_p1 + b_p1)   (wave owns 2 n-tiles)
    mfma_gemm<4, 2>(&s_a[0][0], 264, wpk + PK_P1, w, l, acc2);
    __syncthreads();
    #pragma unroll
    for (int nt = 0; nt < 2; ++nt) {
        const int col = (w * 2 + nt) * 16 + mrow;
        const float bb = b_p1[col];
        #pragma unroll
        for (int i = 0; i < 4; ++i)
            s_a[kg * 4 + i][col] = f2bf(fmaxf(acc2[nt][i] + bb, 0.0f));
    }
    __syncthreads();

    // ---- p2: R = relu(Y @ W_p2 + b_p2)
    mfma_gemm<4, 2>(&s_a[0][0], 264, wpk + PK_P2, w, l, acc2);
    __syncthreads();
    #pragma unroll
    for (int nt = 0; nt < 2; ++nt) {
        const int col = (w * 2 + nt) * 16 + mrow;
        const float bb = b_p2[col];
        #pragma unroll
        for (int i = 0; i < 4; ++i) {
            const float v = fmaxf(acc2[nt][i] + bb, 0.0f);
            s_r[kg * 4 + i][col] = v;
            s_a[kg * 4 + i][col] = f2bf(v);
        }
    }
    __syncthreads();

    // ---- gates: G = [R|hx] @ [W_ih;W_hh] + b   (K=256; wave owns 8 n-tiles)
    {
        f32x4 acc8[8];
        mfma_gemm<8, 8>(&s_a[0][0], 264, wpk + PK_GATES, w, l, acc8);
        #pragma unroll
        for (int nt = 0; nt < 8; ++nt) {
            const int col = (w * 8 + nt) * 16 + mrow;
            const float bb = b_ih[col] + b_hh[col];
            #pragma unroll
            for (int i = 0; i < 4; ++i)
                s_g[kg * 4 + i][col] = acc8[nt][i] + bb;
        }
    }
    __syncthreads();

    // ---- LSTM elementwise (i,f,g,o); features -> s_a bf16
    for (int idx = t; idx < BB * 128; idx += 256) {
        const int r = idx >> 7, j = idx & 127;
        const float ig = s_g[r][j];
        const float fg = s_g[r][j + 128];
        const float gg = s_g[r][j + 256];
        const float og = s_g[r][j + 384];
        const float c_old = cx[(size_t)(r0 + r) * 128 + j];
        const float c_new = sigf(fg) * c_old + sigf(ig) * tanhf(gg);
        const float h_new = sigf(og) * tanhf(c_new);
        out[(size_t)(r0 + r) * 268 + 12 + j]  = h_new;
        out[(size_t)(r0 + r) * 268 + 140 + j] = c_new;
        s_a[r][j] = f2bf(s_r[r][j] + h_new);     // features = reactive + hx_new
    }
    __syncthreads();

    // ---- W_a: H = relu(F @ W_a + b_a)
    mfma_gemm<4, 2>(&s_a[0][0], 264, wpk + PK_WA, w, l, acc2);
    #pragma unroll
    for (int nt = 0; nt < 2; ++nt) {
        const int col = (w * 2 + nt) * 16 + mrow;
        const float bb = b_a[col];
        #pragma unroll
        for (int i = 0; i < 4; ++i)
            s_h[kg * 4 + i][col] = fmaxf(acc2[nt][i] + bb, 0.0f);
    }
    __syncthreads();

    // ---- small heads: 12 scalar outputs per row
    if (t < BB * 12) {
        const int r = t / 12, ww = t % 12;
        const float* Wm; const float* bm; int nc, c, off;
        if (ww < 3)       { Wm = W_mx; bm = b_mx; nc = 3; c = ww;     off = ww; }
        else if (ww < 6)  { Wm = W_my; bm = b_my; nc = 3; c = ww - 3; off = ww; }
        else if (ww < 8)  { Wm = W_fi; bm = b_fi; nc = 2; c = ww - 6; off = ww; }
        else if (ww < 10) { Wm = W_he; bm = b_he; nc = 2; c = ww - 8; off = ww; }
        else if (ww == 10){ Wm = W_ra; bm = b_ra; nc = 1; c = 0;      off = 10; }
        else              { Wm = W_rb; bm = b_rb; nc = 1; c = 0;      off = 11; }
        float acc = bm[c];
        for (int i = 0; i < 128; ++i) acc = fmaf(s_h[r][i], Wm[i * nc + c], acc);
        if (ww >= 10) acc = fmaxf(acc, 0.0f) + log1pf(__expf(-fabsf(acc))) + 1.0f;
        out[(size_t)(r0 + r) * 268 + off] = acc;
    }
}

// ================= fallback Kernel B (fp32 gemv, 512 threads) ===============
__device__ __forceinline__ void gemv128_512(const float (*s_in)[128], float (*s_out)[128],
                                            const float* __restrict__ W,
                                            const float* __restrict__ bvec,
                                            int t, bool relu_)
{
    const int oo = t & 127;
    const int rb = (t >> 7) * 4;
    const float bv = bvec[oo];
    float acc[4];
    #pragma unroll
    for (int r = 0; r < 4; ++r) acc[r] = bv;
    #pragma unroll 4
    for (int i = 0; i < 128; ++i) {
        const float wt = W[i * 128 + oo];
        #pragma unroll
        for (int r = 0; r < 4; ++r) acc[r] = fmaf(s_in[rb + r][i], wt, acc[r]);
    }
    #pragma unroll
    for (int r = 0; r < 4; ++r) s_out[rb + r][oo] = relu_ ? fmaxf(acc[r], 0.0f) : acc[r];
}

__global__ __launch_bounds__(512) void kb_lstm_heads(
    const float* __restrict__ hx, const float* __restrict__ cx,
    const float* __restrict__ W_p1, const float* __restrict__ b_p1,
    const float* __restrict__ W_p2, const float* __restrict__ b_p2,
    const float* __restrict__ W_ih, const float* __restrict__ b_ih,
    const float* __restrict__ W_hh, const float* __restrict__ b_hh,
    const float* __restrict__ W_a,  const float* __restrict__ b_a,
    const float* __restrict__ W_mx, const float* __restrict__ b_mx,
    const float* __restrict__ W_my, const float* __restrict__ b_my,
    const float* __restrict__ W_fi, const float* __restrict__ b_fi,
    const float* __restrict__ W_he, const float* __restrict__ b_he,
    const float* __restrict__ W_ra, const float* __restrict__ b_ra,
    const float* __restrict__ W_rb, const float* __restrict__ b_rb,
    float* out)
{
    const int t = threadIdx.x;
    const int r0 = blockIdx.x * BB;

    __shared__ float s_x[BB][128];
    __shared__ float s_y[BB][128];
    __shared__ float s_hx[BB][128];
    __shared__ float s_g[BB][512];

    for (int idx = t; idx < BB * 128; idx += 512) {
        const int r = idx >> 7, j = idx & 127;
        s_x[r][j]  = out[(size_t)(r0 + r) * 268 + 12 + j];
        s_hx[r][j] = hx[(size_t)(r0 + r) * 128 + j];
    }
    __syncthreads();

    gemv128_512(s_x, s_y, W_p1, b_p1, t, true);
    __syncthreads();
    gemv128_512(s_y, s_x, W_p2, b_p2, t, true);
    __syncthreads();

    {
        float acc[16];
        const float bs = b_ih[t] + b_hh[t];
        #pragma unroll
        for (int r = 0; r < 16; ++r) acc[r] = bs;
        #pragma unroll 4
        for (int i = 0; i < 128; ++i) {
            const float w1 = W_ih[i * 512 + t];
            #pragma unroll
            for (int r = 0; r < 16; ++r) acc[r] = fmaf(s_x[r][i], w1, acc[r]);
        }
        #pragma unroll 4
        for (int i = 0; i < 128; ++i) {
            const float w1 = W_hh[i * 512 + t];
            #pragma unroll
            for (int r = 0; r < 16; ++r) acc[r] = fmaf(s_hx[r][i], w1, acc[r]);
        }
        #pragma unroll
        for (int r = 0; r < 16; ++r) s_g[r][t] = acc[r];
    }
    __syncthreads();

    for (int idx = t; idx < BB * 128; idx += 512) {
        const int r = idx >> 7, j = idx & 127;
        const float ig = s_g[r][j];
        const float fg = s_g[r][j + 128];
        const float gg = s_g[r][j + 256];
        const float og = s_g[r][j + 384];
        const float c_old = cx[(size_t)(r0 + r) * 128 + j];
        const float c_new = sigf(fg) * c_old + sigf(ig) * tanhf(gg);
        const float h_new = sigf(og) * tanhf(c_new);
        out[(size_t)(r0 + r) * 268 + 12 + j]  = h_new;
        out[(size_t)(r0 + r) * 268 + 140 + j] = c_new;
        s_y[r][j] = s_x[r][j] + h_new;
    }
    __syncthreads();

    gemv128_512(s_y, s_x, W_a, b_a, t, true);
    __syncthreads();

    if (t < BB * 12) {
        const int r = t / 12, ww = t % 12;
        const float* Wm; const float* bm; int nc, c, off;
        if (ww < 3)       { Wm = W_mx; bm = b_mx; nc = 3; c = ww;     off = ww; }
        else if (ww < 6)  { Wm = W_my; bm = b_my; nc = 3; c = ww - 3; off = ww; }
        else if (ww < 8)  { Wm = W_fi; bm = b_fi; nc = 2; c = ww - 6; off = ww; }
        else if (ww < 10) { Wm = W_he; bm = b_he; nc = 2; c = ww - 8; off = ww; }
        else if (ww == 10){ Wm = W_ra; bm = b_ra; nc = 1; c = 0;      off = 10; }
        else              { Wm = W_rb; bm = b_rb; nc = 1; c = 0;      off = 11; }
        float acc = bm[c];
        for (int i = 0; i < 128; ++i) acc = fmaf(s_x[r][i], Wm[i * nc + c], acc);
        if (ww >= 10) acc = fmaxf(acc, 0.0f) + log1pf(__expf(-fabsf(acc))) + 1.0f;
        out[(size_t)(r0 + r) * 268 + off] = acc;
    }
}

extern "C" void kernel_launch(void* const* d_in, const int* in_sizes, int n_in,
                              void* d_out, int out_size, void* d_ws, size_t ws_size,
                              hipStream_t stream) {
    (void)n_in; (void)out_size;
    const float* self_feat = (const float*)d_in[0];
    const float* entities  = (const float*)d_in[1];
    const void*  mask      = d_in[2];
    const float* hx  = (const float*)d_in[3];
    const float* cx  = (const float*)d_in[4];
    const float* W_se = (const float*)d_in[5],  *b_se = (const float*)d_in[6];
    const float* W_ee = (const float*)d_in[7],  *b_ee = (const float*)d_in[8];
    const float* W_q  = (const float*)d_in[9],  *b_q  = (const float*)d_in[10];
    const float* W_k  = (const float*)d_in[11], *b_k  = (const float*)d_in[12];
    const float* W_v  = (const float*)d_in[13], *b_v  = (const float*)d_in[14];
    const float* W_p1 = (const float*)d_in[15], *b_p1 = (const float*)d_in[16];
    const float* W_p2 = (const float*)d_in[17], *b_p2 = (const float*)d_in[18];
    const float* W_ih = (const float*)d_in[19], *b_ih = (const float*)d_in[20];
    const float* W_hh = (const float*)d_in[21], *b_hh = (const float*)d_in[22];
    const float* W_a  = (const float*)d_in[23], *b_a  = (const float*)d_in[24];
    const float* W_mx = (const float*)d_in[25], *b_mx = (const float*)d_in[26];
    const float* W_my = (const float*)d_in[27], *b_my = (const float*)d_in[28];
    const float* W_fi = (const float*)d_in[29], *b_fi = (const float*)d_in[30];
    const float* W_he = (const float*)d_in[31], *b_he = (const float*)d_in[32];
    const float* W_ra = (const float*)d_in[33], *b_ra = (const float*)d_in[34];
    const float* W_rb = (const float*)d_in[35], *b_rb = (const float*)d_in[36];
    float* out = (float*)d_out;

    const int B = in_sizes[0] / 24;   // 8192
    const bool use_mfma = ws_size >= (size_t)(PK_TOTAL * 2);

    if (use_mfma) {
        pack_weights<<<PK_TOTAL / 256, 256, 0, stream>>>(
            W_ih, W_hh, W_p1, W_p2, W_a, (unsigned short*)d_ws);
    }

    ka_attention_v5<<<B / 4, 256, 0, stream>>>(self_feat, entities, mask,
        W_se, b_se, W_ee, b_ee, W_q, b_q, W_k, b_k, W_v, b_v, out);

    if (use_mfma) {
        kb_lstm_mfma<<<B / BB, 256, 0, stream>>>(hx, cx, (const unsigned short*)d_ws,
            b_p1, b_p2, b_ih, b_hh, b_a,
            W_mx, b_mx, W_my, b_my, W_fi, b_fi, W_he, b_he, W_ra, b_ra, W_rb, b_rb, out);
    } else {
        kb_lstm_heads<<<B / BB, 512, 0, stream>>>(hx, cx,
            W_p1, b_p1, W_p2, b_p2, W_ih, b_ih, W_hh, b_hh, W_a, b_a,
            W_mx, b_mx, W_my, b_my, W_fi, b_fi, W_he, b_he, W_ra, b_ra, W_rb, b_rb, out);
    }
}